// Round 10
// baseline (432.371 us; speedup 1.0000x reference)
//
#include <hip/hip_runtime.h>

// ---------------------------------------------------------------------------
// BasicTransformerBlock on MI355X (gfx950).
// R19: last unapplied instance of the occupancy lever. GEGLU was register-
// capped at 16 waves/CU (acc 64 + arch 56 = ~120 regs -> 4 waves/SIMD).
// Shrink per-wave acc: 128x64-dual tile, GWM4 GWN4 WM2 WN1, 1024thr MW=8
// (acc 16 + frags 16 + addr ~20 = ~52 <= 64 cap, same envelope as wo-family's
// measured 56). Grid 2048 -> 2 blk/CU x 16 = 32 waves/CU (2x). QKV same:
// 128x64, grid 1536 -> 32 waves/CU (was 24). Staging/FLOP +34% vs 128-wide
// B-panels -- R17 precedent (64x128@32w beat wider@16w) says waves win.
// Everything else frozen at R18 (tanh-GELU kept, absmax 0.031 passed;
// q2kv2 merge kept). Spill detector: WRITE_SIZE must stay 32.8MB on GEGLU.
// ---------------------------------------------------------------------------

typedef _Float16 half8 __attribute__((ext_vector_type(8)));
typedef float f32x4 __attribute__((ext_vector_type(4)));

__device__ __forceinline__ f32x4 mfma16(half8 a, half8 b, f32x4 c) {
  return __builtin_amdgcn_mfma_f32_16x16x32_f16(a, b, c, 0, 0, 0);
}

__device__ __forceinline__ void gload16(const _Float16* g, _Float16* l) {
  __builtin_amdgcn_global_load_lds(
      (const __attribute__((address_space(1))) void*)g,
      (__attribute__((address_space(3))) void*)l, 16, 0, 0);
}

template <int N>
__device__ __forceinline__ void wait_vmcnt() {
  if constexpr (N == 0)
    asm volatile("s_waitcnt vmcnt(0)" ::: "memory");
  else if constexpr (N == 1)
    asm volatile("s_waitcnt vmcnt(1)" ::: "memory");
  else if constexpr (N == 2)
    asm volatile("s_waitcnt vmcnt(2)" ::: "memory");
  else if constexpr (N == 3)
    asm volatile("s_waitcnt vmcnt(3)" ::: "memory");
  else if constexpr (N == 4)
    asm volatile("s_waitcnt vmcnt(4)" ::: "memory");
  else
    static_assert(N <= 4, "add a case");
}

// ---------------- fused prep: 10 weight transposes + enc cvt + LN1 ---------
struct PrepArgs {
  const float* src[10];
  _Float16* dst[10];
  int K[10], N[10], base[10];
  const float* enc;
  _Float16* ench;
  int encBase, nEnc;
  const float* x;
  const float* ln1g;
  const float* ln1b;
  _Float16* hbuf;
  int lnBase;  // first block index of LN rows (8192 rows follow)
};

__global__ __launch_bounds__(256)
void prep_all(PrepArgs pa) {
  __shared__ float tile[32][33];
  const int bid = blockIdx.x;
  const int tx = threadIdx.x, ty = threadIdx.y;
  const int t = ty * 32 + tx;
  if (bid >= pa.lnBase) {
    // -------- LayerNorm1 row --------
    const int row = bid - pa.lnBase;
    const float* xr = pa.x + (size_t)row * 512;
    float v0 = xr[t], v1 = xr[t + 256];
    float s1 = v0 + v1, s2 = v0 * v0 + v1 * v1;
    #pragma unroll
    for (int m = 32; m >= 1; m >>= 1) {
      s1 += __shfl_xor(s1, m);
      s2 += __shfl_xor(s2, m);
    }
    __shared__ float red[8];
    if ((t & 63) == 0) { red[t >> 6] = s1; red[4 + (t >> 6)] = s2; }
    __syncthreads();
    s1 = red[0] + red[1] + red[2] + red[3];
    s2 = red[4] + red[5] + red[6] + red[7];
    const float mu = s1 * (1.0f / 512.0f);
    const float var = s2 * (1.0f / 512.0f) - mu * mu;
    const float rs = rsqrtf(var + 1e-5f);
    pa.hbuf[(size_t)row * 512 + t] =
        (_Float16)((v0 - mu) * rs * pa.ln1g[t] + pa.ln1b[t]);
    pa.hbuf[(size_t)row * 512 + t + 256] =
        (_Float16)((v1 - mu) * rs * pa.ln1g[t + 256] + pa.ln1b[t + 256]);
    return;
  }
  if (bid >= pa.encBase) {
    const int i = (bid - pa.encBase) * 256 + t;
    if (i < pa.nEnc) pa.ench[i] = (_Float16)pa.enc[i];
    return;
  }
  int mi = 0;
  #pragma unroll
  for (int j = 1; j < 10; j++)
    if (bid >= pa.base[j]) mi = j;
  const int K = pa.K[mi], N = pa.N[mi];
  const int rel = bid - pa.base[mi];
  const int ntiles = N >> 5;
  const int bx = rel % ntiles, by = rel / ntiles;
  const float* src = pa.src[mi];
  _Float16* dst = pa.dst[mi];
  const int n0 = bx * 32, k0 = by * 32;
  #pragma unroll
  for (int j = ty; j < 32; j += 8)
    tile[j][tx] = src[(size_t)(k0 + j) * N + n0 + tx];
  __syncthreads();
  #pragma unroll
  for (int j = ty; j < 32; j += 8)
    dst[(size_t)(n0 + j) * K + k0 + tx] = (_Float16)tile[tx][j];
}

// ---------------- V transpose: [b*S+s][h*64+d] -> [(bh*64)+d][s] -----------
__global__ __launch_bounds__(256)
void vt_kernel(const _Float16* __restrict__ src, _Float16* __restrict__ dst,
               int S, int srcStride, int dstStride) {
  __shared__ _Float16 tile[32][33];
  const int tx = threadIdx.x, ty = threadIdx.y;  // (32,8)
  const int s0 = blockIdx.x * 32, d0 = blockIdx.y * 32, bh = blockIdx.z;
  const int b = bh >> 3, h = bh & 7;
  const _Float16* sp = src + (size_t)b * S * srcStride + h * 64 + d0;
  #pragma unroll
  for (int j = ty; j < 32; j += 8) {
    int s = s0 + j; if (s >= S) s = S - 1;
    tile[j][tx] = sp[(size_t)s * srcStride + tx];
  }
  __syncthreads();
  _Float16* dp = dst + ((size_t)bh * 64 + d0) * dstStride + s0;
  #pragma unroll
  for (int j = ty; j < 32; j += 8)
    dp[(size_t)j * dstStride + tx] = tile[tx][j];
}

// ---------------- LayerNorm (row=512), fp32 in -> f16 out ------------------
__global__ __launch_bounds__(256)
void ln_kernel(const float* __restrict__ x, const float* __restrict__ g,
               const float* __restrict__ b, _Float16* __restrict__ out) {
  const int row = blockIdx.x, t = threadIdx.x;
  const float* xr = x + (size_t)row * 512;
  float v0 = xr[t], v1 = xr[t + 256];
  float s1 = v0 + v1, s2 = v0 * v0 + v1 * v1;
  #pragma unroll
  for (int m = 32; m >= 1; m >>= 1) {
    s1 += __shfl_xor(s1, m);
    s2 += __shfl_xor(s2, m);
  }
  __shared__ float red[8];
  if ((t & 63) == 0) { red[t >> 6] = s1; red[4 + (t >> 6)] = s2; }
  __syncthreads();
  s1 = red[0] + red[1] + red[2] + red[3];
  s2 = red[4] + red[5] + red[6] + red[7];
  const float mu = s1 * (1.0f / 512.0f);
  const float var = s2 * (1.0f / 512.0f) - mu * mu;
  const float rs = rsqrtf(var + 1e-5f);
  out[(size_t)row * 512 + t] = (_Float16)((v0 - mu) * rs * g[t] + b[t]);
  out[(size_t)row * 512 + t + 256] =
      (_Float16)((v1 - mu) * rs * g[t + 256] + b[t + 256]);
}

// ---------------- GEMM body: C = A[M,K] @ BT[N,K]^T ------------------------
// PIPE=0: 2-buffer __syncthreads loop. PIPE=1: 3-buffer counted-vmcnt.
// EPI 0: f16 store. EPI 1: Cf = resid + acc + bias. EPI 2: GEGLU dual
// (tanh-GELU). swz: runtime XCD swizzle flag.
template <int EPI, int GWM, int GWN, int WM, int WN, int PIPE>
__device__ __forceinline__ void gemm_body(
    int bid, int swz,
    const _Float16* A, const _Float16* BT,
    int M, int N, int K, int lda, int ldb, int ldc,
    _Float16* Ch, float* Cf, const float* bias, const float* resid) {
  constexpr int NW = GWM * GWN;
  constexpr int BM = GWM * WM * 16;
  constexpr int BN = GWN * WN * 16;
  constexpr int NBUF = PIPE ? 3 : 2;
  constexpr int LPT = (BM / 16) / NW + ((BN / 16) / NW) * ((EPI == 2) ? 2 : 1);
  __shared__ __align__(16) _Float16 As[NBUF][4 * BM * 8];
  __shared__ __align__(16) _Float16 Bs[NBUF][4 * BN * 8];
  __shared__ __align__(16) _Float16 Bs2[(EPI == 2) ? NBUF : 1]
                                      [(EPI == 2) ? 4 * BN * 8 : 8];

  const int t = threadIdx.x;
  const int NNB = (N + BN - 1) / BN;
  int bm, bn;
  if (swz) {
    const int MG = (M / BM) >> 3;
    const int xcd = bid & 7;
    const int s = bid >> 3;
    bm = xcd * MG + s % MG;
    bn = s / MG;
  } else {
    bn = bid % NNB;
    bm = bid / NNB;
  }
  const int m0 = bm * BM, n0 = bn * BN;
  const int lane = t & 63, wv = t >> 6;
  const int quad = lane >> 4, l15 = lane & 15;
  const int wm = wv / GWN, wn = wv % GWN;

  f32x4 zero4 = {0.f, 0.f, 0.f, 0.f};
  f32x4 acc[WM][WN];
  f32x4 acc2[(EPI == 2) ? WM : 1][(EPI == 2) ? WN : 1];
  #pragma unroll
  for (int mi = 0; mi < WM; mi++)
    #pragma unroll
    for (int ni = 0; ni < WN; ni++) acc[mi][ni] = zero4;
  if constexpr (EPI == 2) {
    #pragma unroll
    for (int mi = 0; mi < WM; mi++)
      #pragma unroll
      for (int ni = 0; ni < WN; ni++) acc2[mi][ni] = zero4;
  }

  auto stageAll = [&](int k0, int pb) {
    #pragma unroll
    for (int c = wv; c < BM / 16; c += NW) {
      const int s = c * 64 + lane;
      const int q = s / BM;
      const int r = s % BM;
      int rg = m0 + r; if (rg >= M) rg = M - 1;
      gload16(A + (size_t)rg * lda + k0 + q * 8, &As[pb][c * 512]);
    }
    #pragma unroll
    for (int c = wv; c < BN / 16; c += NW) {
      const int s = c * 64 + lane;
      const int q = s / BN;
      const int r = s % BN;
      gload16(BT + (size_t)(n0 + r) * ldb + k0 + q * 8, &Bs[pb][c * 512]);
      if constexpr (EPI == 2)
        gload16(BT + (size_t)(2048 + n0 + r) * ldb + k0 + q * 8,
                &Bs2[pb][c * 512]);
    }
  };

  auto computeTile = [&](int cur) {
    half8 fa[WM], fb[WN], fb2[(EPI == 2) ? WN : 1];
    #pragma unroll
    for (int mi = 0; mi < WM; mi++)
      fa[mi] = *(const half8*)(&As[cur]
          [((size_t)quad * BM + wm * WM * 16 + mi * 16 + l15) * 8]);
    #pragma unroll
    for (int ni = 0; ni < WN; ni++) {
      fb[ni] = *(const half8*)(&Bs[cur]
          [((size_t)quad * BN + wn * WN * 16 + ni * 16 + l15) * 8]);
      if constexpr (EPI == 2)
        fb2[ni] = *(const half8*)(&Bs2[cur]
            [((size_t)quad * BN + wn * WN * 16 + ni * 16 + l15) * 8]);
    }
    if constexpr (PIPE) __builtin_amdgcn_s_setprio(1);
    #pragma unroll
    for (int mi = 0; mi < WM; mi++)
      #pragma unroll
      for (int ni = 0; ni < WN; ni++) {
        acc[mi][ni] = mfma16(fa[mi], fb[ni], acc[mi][ni]);
        if constexpr (EPI == 2)
          acc2[mi][ni] = mfma16(fa[mi], fb2[ni], acc2[mi][ni]);
      }
    if constexpr (PIPE) __builtin_amdgcn_s_setprio(0);
  };

  const int NIT = K >> 5;
  if constexpr (PIPE) {
    // 3-buffer stage-ahead-2, counted vmcnt.
    stageAll(0, 0);
    if (NIT > 1) stageAll(32, 1);
    int cur = 0, pre = 2;
    for (int it = 0; it < NIT; ++it) {
      if (it + 1 < NIT) wait_vmcnt<LPT>();
      else wait_vmcnt<0>();
      __builtin_amdgcn_s_barrier();
      __builtin_amdgcn_sched_barrier(0);
      computeTile(cur);
      asm volatile("s_waitcnt lgkmcnt(0)" ::: "memory");
      __builtin_amdgcn_sched_barrier(0);
      __builtin_amdgcn_s_barrier();
      if (it + 2 < NIT) stageAll((it + 2) << 5, pre);
      cur = (cur == 2) ? 0 : cur + 1;
      pre = (pre == 2) ? 0 : pre + 1;
    }
  } else {
    // 2-buffer __syncthreads loop.
    stageAll(0, 0);
    __syncthreads();
    for (int it = 0; it < NIT; ++it) {
      const int cur = it & 1;
      if (it + 1 < NIT) stageAll((it + 1) << 5, cur ^ 1);
      computeTile(cur);
      __syncthreads();
    }
  }

  #pragma unroll
  for (int mi = 0; mi < WM; mi++) {
    const int rbase = m0 + wm * WM * 16 + mi * 16 + quad * 4;
    #pragma unroll
    for (int r = 0; r < 4; r++) {
      const int row = rbase + r;
      if (row >= M) continue;
      #pragma unroll
      for (int ni = 0; ni < WN; ni++) {
        const int col = n0 + wn * WN * 16 + ni * 16 + l15;
        const float v = acc[mi][ni][r];
        if constexpr (EPI == 0) {
          Ch[(size_t)row * ldc + col] = (_Float16)v;
        } else if constexpr (EPI == 1) {
          Cf[(size_t)row * ldc + col] =
              resid[(size_t)row * ldc + col] + v + bias[col];
        } else {
          const float u = v + bias[col];
          const float gg = acc2[mi][ni][r] + bias[col + 2048];
          // tanh-approx GELU: 1 exp + 1 rcp + ~6 fma (vs erff ~25-30 ops).
          const float z = 0.7978845608f * gg * (1.0f + 0.044715f * gg * gg);
          const float e2 = exp2f(z * 2.885390082f);   // e^(2z)
          const float th = 1.0f - 2.0f * __builtin_amdgcn_rcpf(e2 + 1.0f);
          const float ge = 0.5f * gg * (1.0f + th);
          Ch[(size_t)row * ldc + col] = (_Float16)(u * ge);
        }
      }
    }
  }
}

template <int EPI, int GWM, int GWN, int WM, int WN, int MW, int SWZ,
          int PIPE>
__global__ __launch_bounds__(GWM * GWN * 64, MW)
void gemm_bt(const _Float16* __restrict__ A, const _Float16* __restrict__ BT,
             int M, int N, int K, int lda, int ldb, int ldc,
             _Float16* Ch, float* Cf,
             const float* __restrict__ bias, const float* resid) {
  gemm_body<EPI, GWM, GWN, WM, WN, PIPE>(blockIdx.x, SWZ, A, BT, M, N, K,
                                         lda, ldb, ldc, Ch, Cf, bias, resid);
}

// Merged q2 (512 swizzled blocks) + kv2 (80 blocks): kv2 alone is 31% CU
// fill; overlapping it under q2 removes a serial tail. Same instantiation
// in both branches -> one LDS allocation; branch is block-uniform.
__global__ __launch_bounds__(1024, 8)
void gemm_q2kv2(const _Float16* hbuf, const _Float16* q2T, _Float16* q2b,
                const _Float16* ench, const _Float16* kv2T, _Float16* kv2b) {
  if (blockIdx.x < 512)
    gemm_body<0, 4, 4, 1, 2, 0>(blockIdx.x, 1, hbuf, q2T,
                                8192, 512, 512, 512, 512, 512,
                                q2b, nullptr, nullptr, nullptr);
  else
    gemm_body<0, 4, 4, 1, 2, 0>(blockIdx.x - 512, 0, ench, kv2T,
                                616, 1024, 768, 768, 768, 1024,
                                kv2b, nullptr, nullptr, nullptr);
}

// ---------------- flash attention v2: 8 waves x 16 Q-rows, 3-buffer --------
// 512 threads. Waves 0-3 stage K tile (32sk x 64d), waves 4-7 stage VT tile
// (64d x 32sk); 1 gload16/thread/stage. Grid (Sq/128, B*H) -> 16 waves/CU.
__global__ __launch_bounds__(512)
void attn2(const _Float16* __restrict__ Q, const _Float16* __restrict__ K,
           const _Float16* __restrict__ VT, _Float16* __restrict__ O,
           int qStride, int kStride, long kBatchStride,
           int vtStride, int Sk) {
  __shared__ __align__(16) _Float16 KsL[3][2048];
  __shared__ __align__(16) _Float16 VTsL[3][2048];
  __shared__ __align__(16) _Float16 Ps[8][16][40];

  const int t = threadIdx.x;
  const int w = t >> 6, lane = t & 63, quad = lane >> 4, l15 = lane & 15;
  const int bh = blockIdx.y, b = bh >> 3, h = bh & 7;
  const int q0 = blockIdx.x * 128 + w * 16;

  const _Float16 qscale = (_Float16)(0.125f * 1.44269504f);
  half8 qf[2];
  #pragma unroll
  for (int c = 0; c < 2; c++) {
    const _Float16* qp = Q + (size_t)(b * 1024 + q0 + l15) * qStride +
                         h * 64 + c * 32 + quad * 8;
    half8 v = *(const half8*)qp;
    #pragma unroll
    for (int j = 0; j < 8; j++) v[j] *= qscale;
    qf[c] = v;
  }

  f32x4 zero4 = {0.f, 0.f, 0.f, 0.f};
  f32x4 oa[4];
  float psum[4];
  #pragma unroll
  for (int nt = 0; nt < 4; nt++) oa[nt] = zero4;
  #pragma unroll
  for (int r = 0; r < 4; r++) psum[r] = 0.f;

  const _Float16* kp = K + (size_t)b * kBatchStride + h * 64;
  const _Float16* vtp = VT + (size_t)bh * 64 * vtStride;
  const bool doK = (t < 256);               // wave-uniform
  const int ts = doK ? t : t - 256;
  const int ksk = ts & 31, kc = ts >> 7, kqd = (ts >> 5) & 3;
  const int vd = ts & 63, vqd = ts >> 6;

  auto stageKV = [&](int skb, int pb) {
    if (doK) {
      int skc = skb + ksk; if (skc >= Sk) skc = Sk - 1;
      gload16(kp + (size_t)skc * kStride + kc * 32 + kqd * 8,
              &KsL[pb][ts * 8]);
    } else {
      gload16(vtp + (size_t)vd * vtStride + skb + vqd * 8,
              &VTsL[pb][ts * 8]);
    }
  };

  const int NITa = (Sk + 31) >> 5;
  stageKV(0, 0);
  if (NITa > 1) stageKV(32, 1);

  int cur = 0, pre = 2;
  int it = 0;
  for (int skb = 0; skb < Sk; skb += 32, ++it) {
    if (it + 1 < NITa) wait_vmcnt<1>();
    else wait_vmcnt<0>();
    __builtin_amdgcn_s_barrier();
    __builtin_amdgcn_sched_barrier(0);

    const bool tail = (skb + 32 > Sk);
    #pragma unroll
    for (int ct = 0; ct < 2; ct++) {
      f32x4 s = zero4;
      half8 kb0 = *(const half8*)(&KsL[cur][(quad * 32 + ct * 16 + l15) * 8]);
      half8 kb1 =
          *(const half8*)(&KsL[cur][(128 + quad * 32 + ct * 16 + l15) * 8]);
      s = mfma16(qf[0], kb0, s);
      s = mfma16(qf[1], kb1, s);
      if (tail) {
        const bool valid = (skb + ct * 16 + l15) < Sk;
        #pragma unroll
        for (int r = 0; r < 4; r++)
          if (!valid) s[r] = -__builtin_inff();
      }
      #pragma unroll
      for (int r = 0; r < 4; r++) {
        const float e = exp2f(s[r]);
        psum[r] += e;
        Ps[w][quad * 4 + r][ct * 16 + l15] = (_Float16)e;
      }
    }
    {
      const half8 pf = *(const half8*)(&Ps[w][l15][quad * 8]);
      #pragma unroll
      for (int nt = 0; nt < 4; nt++) {
        const half8 vf =
            *(const half8*)(&VTsL[cur][(quad * 64 + nt * 16 + l15) * 8]);
        oa[nt] = mfma16(pf, vf, oa[nt]);
      }
    }

    asm volatile("s_waitcnt lgkmcnt(0)" ::: "memory");
    __builtin_amdgcn_sched_barrier(0);
    __builtin_amdgcn_s_barrier();
    if (it + 2 < NITa) stageKV(skb + 64, pre);
    cur = (cur == 2) ? 0 : cur + 1;
    pre = (pre == 2) ? 0 : pre + 1;
  }

  #pragma unroll
  for (int r = 0; r < 4; r++) {
    #pragma unroll
    for (int mm = 1; mm < 16; mm <<= 1)
      psum[r] += __shfl_xor(psum[r], mm);
    psum[r] = 1.0f / psum[r];
  }

  #pragma unroll
  for (int nt = 0; nt < 4; nt++)
    #pragma unroll
    for (int r = 0; r < 4; r++) {
      const size_t row = (size_t)(b * 1024 + q0 + quad * 4 + r);
      O[row * 512 + h * 64 + nt * 16 + l15] =
          (_Float16)(oa[nt][r] * psum[r]);
    }
}

// ---------------------------------------------------------------------------
extern "C" void kernel_launch(void* const* d_in, const int* in_sizes, int n_in,
                              void* d_out, int out_size, void* d_ws,
                              size_t ws_size, hipStream_t stream) {
  const float* x    = (const float*)d_in[0];
  const float* enc  = (const float*)d_in[1];
  const float* ln1g = (const float*)d_in[2];
  const float* ln1b = (const float*)d_in[3];
  const float* wq1  = (const float*)d_in[4];
  const float* wk1  = (const float*)d_in[5];
  const float* wv1  = (const float*)d_in[6];
  const float* wo1  = (const float*)d_in[7];
  const float* bo1  = (const float*)d_in[8];
  const float* ln2g = (const float*)d_in[9];
  const float* ln2b = (const float*)d_in[10];
  const float* wq2  = (const float*)d_in[11];
  const float* wk2  = (const float*)d_in[12];
  const float* wv2  = (const float*)d_in[13];
  const float* wo2  = (const float*)d_in[14];
  const float* bo2  = (const float*)d_in[15];
  const float* ln3g = (const float*)d_in[16];
  const float* ln3b = (const float*)d_in[17];
  const float* wg   = (const float*)d_in[18];
  const float* bg   = (const float*)d_in[19];
  const float* wf   = (const float*)d_in[20];
  const float* bfp  = (const float*)d_in[21];
  float* out = (float*)d_out;

  char* ws = (char*)d_ws;
  _Float16* qkvT  = (_Float16*)(ws + 0);         // [1536,512]
  _Float16* q2T   = (_Float16*)(ws + 1572864);   // [512,512]
  _Float16* kv2T  = (_Float16*)(ws + 2097152);   // [1024,768]
  _Float16* wo1T  = (_Float16*)(ws + 3670016);   // [512,512]
  _Float16* wo2T  = (_Float16*)(ws + 4194304);   // [512,512]
  _Float16* wgT   = (_Float16*)(ws + 4718592);   // [4096,512]
  _Float16* wfT   = (_Float16*)(ws + 8912896);   // [512,2048]
  _Float16* hbuf  = (_Float16*)(ws + 11010048);  // [8192,512] (VTself in attn1)
  _Float16* qkv   = (_Float16*)(ws + 19398656);  // [8192,1536]
  _Float16* q2b   = (_Float16*)(ws + 44564480);  // [8192,512]
  _Float16* kv2b  = (_Float16*)(ws + 52953088);  // [616,1024]
  _Float16* attnb = (_Float16*)(ws + 54214656);  // [8192,512]
  _Float16* ench  = (_Float16*)(ws + 62603264);  // [616,768]
  _Float16* ffb   = (_Float16*)(ws + 19398656);  // [8192,2048] aliases qkv+q2b
  _Float16* VTself = hbuf;                       // [4096,1024]
  _Float16* VTc   = (_Float16*)(ws + 62603264);  // [4096,96] over ench (dead
                                                 // after kv2 GEMM)

  // ---- fused prep: weights + enc + LN1 (one launch) ----
  PrepArgs pa;
  const float* srcs[10] = {wq1, wk1, wv1, wo1, wq2, wk2, wv2, wo2, wg, wf};
  _Float16* dsts[10] = {qkvT, qkvT + 512 * 512, qkvT + 1024 * 512, wo1T, q2T,
                        kv2T, kv2T + 512 * 768, wo2T, wgT, wfT};
  const int Ks[10] = {512, 512, 512, 512, 512, 768, 768, 512, 512, 2048};
  const int Ns[10] = {512, 512, 512, 512, 512, 512, 512, 512, 4096, 512};
  int base = 0;
  for (int i = 0; i < 10; i++) {
    pa.src[i] = srcs[i]; pa.dst[i] = dsts[i];
    pa.K[i] = Ks[i]; pa.N[i] = Ns[i]; pa.base[i] = base;
    base += (Ks[i] >> 5) * (Ns[i] >> 5);
  }
  pa.enc = enc; pa.ench = ench; pa.encBase = base; pa.nEnc = 473088;
  base += (473088 + 255) / 256;
  pa.x = x; pa.ln1g = ln1g; pa.ln1b = ln1b; pa.hbuf = hbuf; pa.lnBase = base;
  base += 8192;
  prep_all<<<base, dim3(32, 8), 0, stream>>>(pa);

  const dim3 tb(32, 8);

  // ---- self-attention block ----
  // QKV: 128x64 tile, 16 waves (R19), grid 1536 -> 2 blk/CU x 16 = 32 w/CU
  gemm_bt<0, 4, 4, 2, 1, 8, 1, 0><<<1536, 1024, 0, stream>>>(
      hbuf, qkvT, 8192, 1536, 512, 512, 512, 1536,
      qkv, nullptr, nullptr, nullptr);
  vt_kernel<<<dim3(32, 2, 64), tb, 0, stream>>>(qkv + 1024, VTself, 1024,
                                                1536, 1024);
  attn2<<<dim3(8, 64), 512, 0, stream>>>(qkv, qkv + 512, VTself, attnb,
                                         1536, 1536, (long)1024 * 1536,
                                         1024, 1024);
  // wo1: 64x128 tile, 16 waves, grid 512 -> 32 waves/CU (R17)
  gemm_bt<1, 4, 4, 1, 2, 8, 1, 0><<<512, 1024, 0, stream>>>(
      attnb, wo1T, 8192, 512, 512, 512, 512, 512, nullptr, out, bo1, x);

  // ---- cross-attention block ----
  ln_kernel<<<8192, 256, 0, stream>>>(out, ln2g, ln2b, hbuf);
  // q2 + kv2 merged (R18): 512 + 80 blocks, kv2 overlapped under q2
  gemm_q2kv2<<<592, 1024, 0, stream>>>(hbuf, q2T, q2b, ench, kv2T, kv2b);
  vt_kernel<<<dim3(3, 2, 64), tb, 0, stream>>>(kv2b + 512, VTc, 77, 1024, 96);
  attn2<<<dim3(8, 64), 512, 0, stream>>>(q2b, kv2b, VTc, attnb,
                                         512, 1024, (long)77 * 1024, 96, 77);
  gemm_bt<1, 4, 4, 1, 2, 8, 1, 0><<<512, 1024, 0, stream>>>(
      attnb, wo2T, 8192, 512, 512, 512, 512, 512, nullptr, out, bo2, out);

  // ---- GEGLU feed-forward ----
  ln_kernel<<<8192, 256, 0, stream>>>(out, ln3g, ln3b, hbuf);
  // GEGLU: 128x64-dual, 16 waves (R19), grid 2048 -> 2 blk/CU x 16 =
  // 32 waves/CU (was reg-capped at 16). acc 16 + frags 16 regs <= 64 cap.
  gemm_bt<2, 4, 4, 2, 1, 8, 1, 0><<<2048, 1024, 0, stream>>>(
      hbuf, wgT, 8192, 2048, 512, 512, 512, 2048,
      ffb, nullptr, bg, nullptr);
  // wf: 64x128 tile, 16 waves, grid 512 -> 32 waves/CU (R17)
  gemm_bt<1, 4, 4, 1, 2, 8, 1, 0><<<512, 1024, 0, stream>>>(
      ffb, wfT, 8192, 512, 2048, 2048, 2048, 512,
      nullptr, out, bfp, out);
}

// Round 11
// 420.250 us; speedup vs baseline: 1.0288x; 1.0288x over previous
//
#include <hip/hip_runtime.h>

// ---------------------------------------------------------------------------
// BasicTransformerBlock on MI355X (gfx950).
// R20: revert to R18 (measured best, 418.3us). R19 falsified the last open
// lever: GEGLU at 32 waves/CU (occ 78%, VGPR 24, no spill) was WORSE (85.7
// vs 81.6) because WM2xWN1 doubles ds_read-per-MFMA (0.5 -> 1.0). At 8 waves
// + dual acc, reads/MFMA is minimized at WM*WN=8 = exactly R18's config ->
// config space closed. Ledger: schedule axis null (R9/R10/R13), tile axis
// optimum at R18 values (R11/R14/R19), wave axis saturated at 16/CU GEMM +
// 32/CU wo-family (R15-R17), epilogue tanh-GELU (-3.8us, R18), q2+kv2 merge
// (R18). Remaining guide lever (8-phase 256^2) is regime-gated to 256^2
// tiles which underfill these shapes (N=512/2048 -> 64-block grids).
// ---------------------------------------------------------------------------

typedef _Float16 half8 __attribute__((ext_vector_type(8)));
typedef float f32x4 __attribute__((ext_vector_type(4)));

__device__ __forceinline__ f32x4 mfma16(half8 a, half8 b, f32x4 c) {
  return __builtin_amdgcn_mfma_f32_16x16x32_f16(a, b, c, 0, 0, 0);
}

__device__ __forceinline__ void gload16(const _Float16* g, _Float16* l) {
  __builtin_amdgcn_global_load_lds(
      (const __attribute__((address_space(1))) void*)g,
      (__attribute__((address_space(3))) void*)l, 16, 0, 0);
}

template <int N>
__device__ __forceinline__ void wait_vmcnt() {
  if constexpr (N == 0)
    asm volatile("s_waitcnt vmcnt(0)" ::: "memory");
  else if constexpr (N == 1)
    asm volatile("s_waitcnt vmcnt(1)" ::: "memory");
  else if constexpr (N == 2)
    asm volatile("s_waitcnt vmcnt(2)" ::: "memory");
  else if constexpr (N == 3)
    asm volatile("s_waitcnt vmcnt(3)" ::: "memory");
  else if constexpr (N == 4)
    asm volatile("s_waitcnt vmcnt(4)" ::: "memory");
  else
    static_assert(N <= 4, "add a case");
}

// ---------------- fused prep: 10 weight transposes + enc cvt + LN1 ---------
struct PrepArgs {
  const float* src[10];
  _Float16* dst[10];
  int K[10], N[10], base[10];
  const float* enc;
  _Float16* ench;
  int encBase, nEnc;
  const float* x;
  const float* ln1g;
  const float* ln1b;
  _Float16* hbuf;
  int lnBase;  // first block index of LN rows (8192 rows follow)
};

__global__ __launch_bounds__(256)
void prep_all(PrepArgs pa) {
  __shared__ float tile[32][33];
  const int bid = blockIdx.x;
  const int tx = threadIdx.x, ty = threadIdx.y;
  const int t = ty * 32 + tx;
  if (bid >= pa.lnBase) {
    // -------- LayerNorm1 row --------
    const int row = bid - pa.lnBase;
    const float* xr = pa.x + (size_t)row * 512;
    float v0 = xr[t], v1 = xr[t + 256];
    float s1 = v0 + v1, s2 = v0 * v0 + v1 * v1;
    #pragma unroll
    for (int m = 32; m >= 1; m >>= 1) {
      s1 += __shfl_xor(s1, m);
      s2 += __shfl_xor(s2, m);
    }
    __shared__ float red[8];
    if ((t & 63) == 0) { red[t >> 6] = s1; red[4 + (t >> 6)] = s2; }
    __syncthreads();
    s1 = red[0] + red[1] + red[2] + red[3];
    s2 = red[4] + red[5] + red[6] + red[7];
    const float mu = s1 * (1.0f / 512.0f);
    const float var = s2 * (1.0f / 512.0f) - mu * mu;
    const float rs = rsqrtf(var + 1e-5f);
    pa.hbuf[(size_t)row * 512 + t] =
        (_Float16)((v0 - mu) * rs * pa.ln1g[t] + pa.ln1b[t]);
    pa.hbuf[(size_t)row * 512 + t + 256] =
        (_Float16)((v1 - mu) * rs * pa.ln1g[t + 256] + pa.ln1b[t + 256]);
    return;
  }
  if (bid >= pa.encBase) {
    const int i = (bid - pa.encBase) * 256 + t;
    if (i < pa.nEnc) pa.ench[i] = (_Float16)pa.enc[i];
    return;
  }
  int mi = 0;
  #pragma unroll
  for (int j = 1; j < 10; j++)
    if (bid >= pa.base[j]) mi = j;
  const int K = pa.K[mi], N = pa.N[mi];
  const int rel = bid - pa.base[mi];
  const int ntiles = N >> 5;
  const int bx = rel % ntiles, by = rel / ntiles;
  const float* src = pa.src[mi];
  _Float16* dst = pa.dst[mi];
  const int n0 = bx * 32, k0 = by * 32;
  #pragma unroll
  for (int j = ty; j < 32; j += 8)
    tile[j][tx] = src[(size_t)(k0 + j) * N + n0 + tx];
  __syncthreads();
  #pragma unroll
  for (int j = ty; j < 32; j += 8)
    dst[(size_t)(n0 + j) * K + k0 + tx] = (_Float16)tile[tx][j];
}

// ---------------- V transpose: [b*S+s][h*64+d] -> [(bh*64)+d][s] -----------
__global__ __launch_bounds__(256)
void vt_kernel(const _Float16* __restrict__ src, _Float16* __restrict__ dst,
               int S, int srcStride, int dstStride) {
  __shared__ _Float16 tile[32][33];
  const int tx = threadIdx.x, ty = threadIdx.y;  // (32,8)
  const int s0 = blockIdx.x * 32, d0 = blockIdx.y * 32, bh = blockIdx.z;
  const int b = bh >> 3, h = bh & 7;
  const _Float16* sp = src + (size_t)b * S * srcStride + h * 64 + d0;
  #pragma unroll
  for (int j = ty; j < 32; j += 8) {
    int s = s0 + j; if (s >= S) s = S - 1;
    tile[j][tx] = sp[(size_t)s * srcStride + tx];
  }
  __syncthreads();
  _Float16* dp = dst + ((size_t)bh * 64 + d0) * dstStride + s0;
  #pragma unroll
  for (int j = ty; j < 32; j += 8)
    dp[(size_t)j * dstStride + tx] = tile[tx][j];
}

// ---------------- LayerNorm (row=512), fp32 in -> f16 out ------------------
__global__ __launch_bounds__(256)
void ln_kernel(const float* __restrict__ x, const float* __restrict__ g,
               const float* __restrict__ b, _Float16* __restrict__ out) {
  const int row = blockIdx.x, t = threadIdx.x;
  const float* xr = x + (size_t)row * 512;
  float v0 = xr[t], v1 = xr[t + 256];
  float s1 = v0 + v1, s2 = v0 * v0 + v1 * v1;
  #pragma unroll
  for (int m = 32; m >= 1; m >>= 1) {
    s1 += __shfl_xor(s1, m);
    s2 += __shfl_xor(s2, m);
  }
  __shared__ float red[8];
  if ((t & 63) == 0) { red[t >> 6] = s1; red[4 + (t >> 6)] = s2; }
  __syncthreads();
  s1 = red[0] + red[1] + red[2] + red[3];
  s2 = red[4] + red[5] + red[6] + red[7];
  const float mu = s1 * (1.0f / 512.0f);
  const float var = s2 * (1.0f / 512.0f) - mu * mu;
  const float rs = rsqrtf(var + 1e-5f);
  out[(size_t)row * 512 + t] = (_Float16)((v0 - mu) * rs * g[t] + b[t]);
  out[(size_t)row * 512 + t + 256] =
      (_Float16)((v1 - mu) * rs * g[t + 256] + b[t + 256]);
}

// ---------------- GEMM body: C = A[M,K] @ BT[N,K]^T ------------------------
// PIPE=0: 2-buffer __syncthreads loop. PIPE=1: 3-buffer counted-vmcnt.
// EPI 0: f16 store. EPI 1: Cf = resid + acc + bias. EPI 2: GEGLU dual
// (tanh-GELU). swz: runtime XCD swizzle flag.
template <int EPI, int GWM, int GWN, int WM, int WN, int PIPE>
__device__ __forceinline__ void gemm_body(
    int bid, int swz,
    const _Float16* A, const _Float16* BT,
    int M, int N, int K, int lda, int ldb, int ldc,
    _Float16* Ch, float* Cf, const float* bias, const float* resid) {
  constexpr int NW = GWM * GWN;
  constexpr int BM = GWM * WM * 16;
  constexpr int BN = GWN * WN * 16;
  constexpr int NBUF = PIPE ? 3 : 2;
  constexpr int LPT = (BM / 16) / NW + ((BN / 16) / NW) * ((EPI == 2) ? 2 : 1);
  __shared__ __align__(16) _Float16 As[NBUF][4 * BM * 8];
  __shared__ __align__(16) _Float16 Bs[NBUF][4 * BN * 8];
  __shared__ __align__(16) _Float16 Bs2[(EPI == 2) ? NBUF : 1]
                                      [(EPI == 2) ? 4 * BN * 8 : 8];

  const int t = threadIdx.x;
  const int NNB = (N + BN - 1) / BN;
  int bm, bn;
  if (swz) {
    const int MG = (M / BM) >> 3;
    const int xcd = bid & 7;
    const int s = bid >> 3;
    bm = xcd * MG + s % MG;
    bn = s / MG;
  } else {
    bn = bid % NNB;
    bm = bid / NNB;
  }
  const int m0 = bm * BM, n0 = bn * BN;
  const int lane = t & 63, wv = t >> 6;
  const int quad = lane >> 4, l15 = lane & 15;
  const int wm = wv / GWN, wn = wv % GWN;

  f32x4 zero4 = {0.f, 0.f, 0.f, 0.f};
  f32x4 acc[WM][WN];
  f32x4 acc2[(EPI == 2) ? WM : 1][(EPI == 2) ? WN : 1];
  #pragma unroll
  for (int mi = 0; mi < WM; mi++)
    #pragma unroll
    for (int ni = 0; ni < WN; ni++) acc[mi][ni] = zero4;
  if constexpr (EPI == 2) {
    #pragma unroll
    for (int mi = 0; mi < WM; mi++)
      #pragma unroll
      for (int ni = 0; ni < WN; ni++) acc2[mi][ni] = zero4;
  }

  auto stageAll = [&](int k0, int pb) {
    #pragma unroll
    for (int c = wv; c < BM / 16; c += NW) {
      const int s = c * 64 + lane;
      const int q = s / BM;
      const int r = s % BM;
      int rg = m0 + r; if (rg >= M) rg = M - 1;
      gload16(A + (size_t)rg * lda + k0 + q * 8, &As[pb][c * 512]);
    }
    #pragma unroll
    for (int c = wv; c < BN / 16; c += NW) {
      const int s = c * 64 + lane;
      const int q = s / BN;
      const int r = s % BN;
      gload16(BT + (size_t)(n0 + r) * ldb + k0 + q * 8, &Bs[pb][c * 512]);
      if constexpr (EPI == 2)
        gload16(BT + (size_t)(2048 + n0 + r) * ldb + k0 + q * 8,
                &Bs2[pb][c * 512]);
    }
  };

  auto computeTile = [&](int cur) {
    half8 fa[WM], fb[WN], fb2[(EPI == 2) ? WN : 1];
    #pragma unroll
    for (int mi = 0; mi < WM; mi++)
      fa[mi] = *(const half8*)(&As[cur]
          [((size_t)quad * BM + wm * WM * 16 + mi * 16 + l15) * 8]);
    #pragma unroll
    for (int ni = 0; ni < WN; ni++) {
      fb[ni] = *(const half8*)(&Bs[cur]
          [((size_t)quad * BN + wn * WN * 16 + ni * 16 + l15) * 8]);
      if constexpr (EPI == 2)
        fb2[ni] = *(const half8*)(&Bs2[cur]
            [((size_t)quad * BN + wn * WN * 16 + ni * 16 + l15) * 8]);
    }
    if constexpr (PIPE) __builtin_amdgcn_s_setprio(1);
    #pragma unroll
    for (int mi = 0; mi < WM; mi++)
      #pragma unroll
      for (int ni = 0; ni < WN; ni++) {
        acc[mi][ni] = mfma16(fa[mi], fb[ni], acc[mi][ni]);
        if constexpr (EPI == 2)
          acc2[mi][ni] = mfma16(fa[mi], fb2[ni], acc2[mi][ni]);
      }
    if constexpr (PIPE) __builtin_amdgcn_s_setprio(0);
  };

  const int NIT = K >> 5;
  if constexpr (PIPE) {
    // 3-buffer stage-ahead-2, counted vmcnt.
    stageAll(0, 0);
    if (NIT > 1) stageAll(32, 1);
    int cur = 0, pre = 2;
    for (int it = 0; it < NIT; ++it) {
      if (it + 1 < NIT) wait_vmcnt<LPT>();
      else wait_vmcnt<0>();
      __builtin_amdgcn_s_barrier();
      __builtin_amdgcn_sched_barrier(0);
      computeTile(cur);
      asm volatile("s_waitcnt lgkmcnt(0)" ::: "memory");
      __builtin_amdgcn_sched_barrier(0);
      __builtin_amdgcn_s_barrier();
      if (it + 2 < NIT) stageAll((it + 2) << 5, pre);
      cur = (cur == 2) ? 0 : cur + 1;
      pre = (pre == 2) ? 0 : pre + 1;
    }
  } else {
    // 2-buffer __syncthreads loop.
    stageAll(0, 0);
    __syncthreads();
    for (int it = 0; it < NIT; ++it) {
      const int cur = it & 1;
      if (it + 1 < NIT) stageAll((it + 1) << 5, cur ^ 1);
      computeTile(cur);
      __syncthreads();
    }
  }

  #pragma unroll
  for (int mi = 0; mi < WM; mi++) {
    const int rbase = m0 + wm * WM * 16 + mi * 16 + quad * 4;
    #pragma unroll
    for (int r = 0; r < 4; r++) {
      const int row = rbase + r;
      if (row >= M) continue;
      #pragma unroll
      for (int ni = 0; ni < WN; ni++) {
        const int col = n0 + wn * WN * 16 + ni * 16 + l15;
        const float v = acc[mi][ni][r];
        if constexpr (EPI == 0) {
          Ch[(size_t)row * ldc + col] = (_Float16)v;
        } else if constexpr (EPI == 1) {
          Cf[(size_t)row * ldc + col] =
              resid[(size_t)row * ldc + col] + v + bias[col];
        } else {
          const float u = v + bias[col];
          const float gg = acc2[mi][ni][r] + bias[col + 2048];
          // tanh-approx GELU: 1 exp + 1 rcp + ~6 fma (vs erff ~25-30 ops).
          const float z = 0.7978845608f * gg * (1.0f + 0.044715f * gg * gg);
          const float e2 = exp2f(z * 2.885390082f);   // e^(2z)
          const float th = 1.0f - 2.0f * __builtin_amdgcn_rcpf(e2 + 1.0f);
          const float ge = 0.5f * gg * (1.0f + th);
          Ch[(size_t)row * ldc + col] = (_Float16)(u * ge);
        }
      }
    }
  }
}

template <int EPI, int GWM, int GWN, int WM, int WN, int MW, int SWZ,
          int PIPE>
__global__ __launch_bounds__(GWM * GWN * 64, MW)
void gemm_bt(const _Float16* __restrict__ A, const _Float16* __restrict__ BT,
             int M, int N, int K, int lda, int ldb, int ldc,
             _Float16* Ch, float* Cf,
             const float* __restrict__ bias, const float* resid) {
  gemm_body<EPI, GWM, GWN, WM, WN, PIPE>(blockIdx.x, SWZ, A, BT, M, N, K,
                                         lda, ldb, ldc, Ch, Cf, bias, resid);
}

// Merged q2 (512 swizzled blocks) + kv2 (80 blocks): kv2 alone is 31% CU
// fill; overlapping it under q2 removes a serial tail. Same instantiation
// in both branches -> one LDS allocation; branch is block-uniform.
__global__ __launch_bounds__(1024, 8)
void gemm_q2kv2(const _Float16* hbuf, const _Float16* q2T, _Float16* q2b,
                const _Float16* ench, const _Float16* kv2T, _Float16* kv2b) {
  if (blockIdx.x < 512)
    gemm_body<0, 4, 4, 1, 2, 0>(blockIdx.x, 1, hbuf, q2T,
                                8192, 512, 512, 512, 512, 512,
                                q2b, nullptr, nullptr, nullptr);
  else
    gemm_body<0, 4, 4, 1, 2, 0>(blockIdx.x - 512, 0, ench, kv2T,
                                616, 1024, 768, 768, 768, 1024,
                                kv2b, nullptr, nullptr, nullptr);
}

// ---------------- flash attention v2: 8 waves x 16 Q-rows, 3-buffer --------
// 512 threads. Waves 0-3 stage K tile (32sk x 64d), waves 4-7 stage VT tile
// (64d x 32sk); 1 gload16/thread/stage. Grid (Sq/128, B*H) -> 16 waves/CU.
__global__ __launch_bounds__(512)
void attn2(const _Float16* __restrict__ Q, const _Float16* __restrict__ K,
           const _Float16* __restrict__ VT, _Float16* __restrict__ O,
           int qStride, int kStride, long kBatchStride,
           int vtStride, int Sk) {
  __shared__ __align__(16) _Float16 KsL[3][2048];
  __shared__ __align__(16) _Float16 VTsL[3][2048];
  __shared__ __align__(16) _Float16 Ps[8][16][40];

  const int t = threadIdx.x;
  const int w = t >> 6, lane = t & 63, quad = lane >> 4, l15 = lane & 15;
  const int bh = blockIdx.y, b = bh >> 3, h = bh & 7;
  const int q0 = blockIdx.x * 128 + w * 16;

  const _Float16 qscale = (_Float16)(0.125f * 1.44269504f);
  half8 qf[2];
  #pragma unroll
  for (int c = 0; c < 2; c++) {
    const _Float16* qp = Q + (size_t)(b * 1024 + q0 + l15) * qStride +
                         h * 64 + c * 32 + quad * 8;
    half8 v = *(const half8*)qp;
    #pragma unroll
    for (int j = 0; j < 8; j++) v[j] *= qscale;
    qf[c] = v;
  }

  f32x4 zero4 = {0.f, 0.f, 0.f, 0.f};
  f32x4 oa[4];
  float psum[4];
  #pragma unroll
  for (int nt = 0; nt < 4; nt++) oa[nt] = zero4;
  #pragma unroll
  for (int r = 0; r < 4; r++) psum[r] = 0.f;

  const _Float16* kp = K + (size_t)b * kBatchStride + h * 64;
  const _Float16* vtp = VT + (size_t)bh * 64 * vtStride;
  const bool doK = (t < 256);               // wave-uniform
  const int ts = doK ? t : t - 256;
  const int ksk = ts & 31, kc = ts >> 7, kqd = (ts >> 5) & 3;
  const int vd = ts & 63, vqd = ts >> 6;

  auto stageKV = [&](int skb, int pb) {
    if (doK) {
      int skc = skb + ksk; if (skc >= Sk) skc = Sk - 1;
      gload16(kp + (size_t)skc * kStride + kc * 32 + kqd * 8,
              &KsL[pb][ts * 8]);
    } else {
      gload16(vtp + (size_t)vd * vtStride + skb + vqd * 8,
              &VTsL[pb][ts * 8]);
    }
  };

  const int NITa = (Sk + 31) >> 5;
  stageKV(0, 0);
  if (NITa > 1) stageKV(32, 1);

  int cur = 0, pre = 2;
  int it = 0;
  for (int skb = 0; skb < Sk; skb += 32, ++it) {
    if (it + 1 < NITa) wait_vmcnt<1>();
    else wait_vmcnt<0>();
    __builtin_amdgcn_s_barrier();
    __builtin_amdgcn_sched_barrier(0);

    const bool tail = (skb + 32 > Sk);
    #pragma unroll
    for (int ct = 0; ct < 2; ct++) {
      f32x4 s = zero4;
      half8 kb0 = *(const half8*)(&KsL[cur][(quad * 32 + ct * 16 + l15) * 8]);
      half8 kb1 =
          *(const half8*)(&KsL[cur][(128 + quad * 32 + ct * 16 + l15) * 8]);
      s = mfma16(qf[0], kb0, s);
      s = mfma16(qf[1], kb1, s);
      if (tail) {
        const bool valid = (skb + ct * 16 + l15) < Sk;
        #pragma unroll
        for (int r = 0; r < 4; r++)
          if (!valid) s[r] = -__builtin_inff();
      }
      #pragma unroll
      for (int r = 0; r < 4; r++) {
        const float e = exp2f(s[r]);
        psum[r] += e;
        Ps[w][quad * 4 + r][ct * 16 + l15] = (_Float16)e;
      }
    }
    {
      const half8 pf = *(const half8*)(&Ps[w][l15][quad * 8]);
      #pragma unroll
      for (int nt = 0; nt < 4; nt++) {
        const half8 vf =
            *(const half8*)(&VTsL[cur][(quad * 64 + nt * 16 + l15) * 8]);
        oa[nt] = mfma16(pf, vf, oa[nt]);
      }
    }

    asm volatile("s_waitcnt lgkmcnt(0)" ::: "memory");
    __builtin_amdgcn_sched_barrier(0);
    __builtin_amdgcn_s_barrier();
    if (it + 2 < NITa) stageKV(skb + 64, pre);
    cur = (cur == 2) ? 0 : cur + 1;
    pre = (pre == 2) ? 0 : pre + 1;
  }

  #pragma unroll
  for (int r = 0; r < 4; r++) {
    #pragma unroll
    for (int mm = 1; mm < 16; mm <<= 1)
      psum[r] += __shfl_xor(psum[r], mm);
    psum[r] = 1.0f / psum[r];
  }

  #pragma unroll
  for (int nt = 0; nt < 4; nt++)
    #pragma unroll
    for (int r = 0; r < 4; r++) {
      const size_t row = (size_t)(b * 1024 + q0 + quad * 4 + r);
      O[row * 512 + h * 64 + nt * 16 + l15] =
          (_Float16)(oa[nt][r] * psum[r]);
    }
}

// ---------------------------------------------------------------------------
extern "C" void kernel_launch(void* const* d_in, const int* in_sizes, int n_in,
                              void* d_out, int out_size, void* d_ws,
                              size_t ws_size, hipStream_t stream) {
  const float* x    = (const float*)d_in[0];
  const float* enc  = (const float*)d_in[1];
  const float* ln1g = (const float*)d_in[2];
  const float* ln1b = (const float*)d_in[3];
  const float* wq1  = (const float*)d_in[4];
  const float* wk1  = (const float*)d_in[5];
  const float* wv1  = (const float*)d_in[6];
  const float* wo1  = (const float*)d_in[7];
  const float* bo1  = (const float*)d_in[8];
  const float* ln2g = (const float*)d_in[9];
  const float* ln2b = (const float*)d_in[10];
  const float* wq2  = (const float*)d_in[11];
  const float* wk2  = (const float*)d_in[12];
  const float* wv2  = (const float*)d_in[13];
  const float* wo2  = (const float*)d_in[14];
  const float* bo2  = (const float*)d_in[15];
  const float* ln3g = (const float*)d_in[16];
  const float* ln3b = (const float*)d_in[17];
  const float* wg   = (const float*)d_in[18];
  const float* bg   = (const float*)d_in[19];
  const float* wf   = (const float*)d_in[20];
  const float* bfp  = (const float*)d_in[21];
  float* out = (float*)d_out;

  char* ws = (char*)d_ws;
  _Float16* qkvT  = (_Float16*)(ws + 0);         // [1536,512]
  _Float16* q2T   = (_Float16*)(ws + 1572864);   // [512,512]
  _Float16* kv2T  = (_Float16*)(ws + 2097152);   // [1024,768]
  _Float16* wo1T  = (_Float16*)(ws + 3670016);   // [512,512]
  _Float16* wo2T  = (_Float16*)(ws + 4194304);   // [512,512]
  _Float16* wgT   = (_Float16*)(ws + 4718592);   // [4096,512]
  _Float16* wfT   = (_Float16*)(ws + 8912896);   // [512,2048]
  _Float16* hbuf  = (_Float16*)(ws + 11010048);  // [8192,512] (VTself in attn1)
  _Float16* qkv   = (_Float16*)(ws + 19398656);  // [8192,1536]
  _Float16* q2b   = (_Float16*)(ws + 44564480);  // [8192,512]
  _Float16* kv2b  = (_Float16*)(ws + 52953088);  // [616,1024]
  _Float16* attnb = (_Float16*)(ws + 54214656);  // [8192,512]
  _Float16* ench  = (_Float16*)(ws + 62603264);  // [616,768]
  _Float16* ffb   = (_Float16*)(ws + 19398656);  // [8192,2048] aliases qkv+q2b
  _Float16* VTself = hbuf;                       // [4096,1024]
  _Float16* VTc   = (_Float16*)(ws + 62603264);  // [4096,96] over ench (dead
                                                 // after kv2 GEMM)

  // ---- fused prep: weights + enc + LN1 (one launch) ----
  PrepArgs pa;
  const float* srcs[10] = {wq1, wk1, wv1, wo1, wq2, wk2, wv2, wo2, wg, wf};
  _Float16* dsts[10] = {qkvT, qkvT + 512 * 512, qkvT + 1024 * 512, wo1T, q2T,
                        kv2T, kv2T + 512 * 768, wo2T, wgT, wfT};
  const int Ks[10] = {512, 512, 512, 512, 512, 768, 768, 512, 512, 2048};
  const int Ns[10] = {512, 512, 512, 512, 512, 512, 512, 512, 4096, 512};
  int base = 0;
  for (int i = 0; i < 10; i++) {
    pa.src[i] = srcs[i]; pa.dst[i] = dsts[i];
    pa.K[i] = Ks[i]; pa.N[i] = Ns[i]; pa.base[i] = base;
    base += (Ks[i] >> 5) * (Ns[i] >> 5);
  }
  pa.enc = enc; pa.ench = ench; pa.encBase = base; pa.nEnc = 473088;
  base += (473088 + 255) / 256;
  pa.x = x; pa.ln1g = ln1g; pa.ln1b = ln1b; pa.hbuf = hbuf; pa.lnBase = base;
  base += 8192;
  prep_all<<<base, dim3(32, 8), 0, stream>>>(pa);

  const dim3 tb(32, 8);

  // ---- self-attention block ----
  // QKV: 128x128 tile, 8 waves, grid 768 (R16/R18)
  gemm_bt<0, 2, 4, 4, 2, 4, 1, 0><<<768, 512, 0, stream>>>(
      hbuf, qkvT, 8192, 1536, 512, 512, 512, 1536,
      qkv, nullptr, nullptr, nullptr);
  vt_kernel<<<dim3(32, 2, 64), tb, 0, stream>>>(qkv + 1024, VTself, 1024,
                                                1536, 1024);
  attn2<<<dim3(8, 64), 512, 0, stream>>>(qkv, qkv + 512, VTself, attnb,
                                         1536, 1536, (long)1024 * 1536,
                                         1024, 1024);
  // wo1: 64x128 tile, 16 waves, grid 512 -> 32 waves/CU (R17)
  gemm_bt<1, 4, 4, 1, 2, 8, 1, 0><<<512, 1024, 0, stream>>>(
      attnb, wo1T, 8192, 512, 512, 512, 512, 512, nullptr, out, bo1, x);

  // ---- cross-attention block ----
  ln_kernel<<<8192, 256, 0, stream>>>(out, ln2g, ln2b, hbuf);
  // q2 + kv2 merged (R18): 512 + 80 blocks, kv2 overlapped under q2
  gemm_q2kv2<<<592, 1024, 0, stream>>>(hbuf, q2T, q2b, ench, kv2T, kv2b);
  vt_kernel<<<dim3(3, 2, 64), tb, 0, stream>>>(kv2b + 512, VTc, 77, 1024, 96);
  attn2<<<dim3(8, 64), 512, 0, stream>>>(q2b, kv2b, VTc, attnb,
                                         512, 1024, (long)77 * 1024, 96, 77);
  gemm_bt<1, 4, 4, 1, 2, 8, 1, 0><<<512, 1024, 0, stream>>>(
      attnb, wo2T, 8192, 512, 512, 512, 512, 512, nullptr, out, bo2, out);

  // ---- GEGLU feed-forward ----
  ln_kernel<<<8192, 256, 0, stream>>>(out, ln3g, ln3b, hbuf);
  // GEGLU: 128x128-dual, 8 waves (R14 config) + tanh-GELU epilogue (R18).
  // WM4xWN2-dual = 0.5 ds_read/MFMA, the optimum under the 64-acc-reg cap.
  gemm_bt<2, 2, 4, 4, 2, 4, 1, 0><<<1024, 512, 0, stream>>>(
      hbuf, wgT, 8192, 2048, 512, 512, 512, 2048,
      ffb, nullptr, bg, nullptr);
  // wf: 64x128 tile, 16 waves, grid 512 -> 32 waves/CU (R17)
  gemm_bt<1, 4, 4, 1, 2, 8, 1, 0><<<512, 1024, 0, stream>>>(
      ffb, wfT, 8192, 512, 2048, 2048, 2048, 512,
      nullptr, out, bfp, out);
}

// Round 12
// 415.177 us; speedup vs baseline: 1.0414x; 1.0122x over previous
//
#include <hip/hip_runtime.h>

// ---------------------------------------------------------------------------
// BasicTransformerBlock on MI355X (gfx950).
// R21: R20 reproduced R18 (420.2 ~ 418.3, band +-2). GEMM/attn config space
// closed (see R20 header). This round: the serial small-kernel chain, pure
// G13 bandwidth fixes, zero risk to the tuned kernels:
//  (1) prep transposes: 64x64 tiles, float2 reads, packed f16x2 writes
//      (was 4B-read/2B-write scalar), 1/4 the blocks.
//  (2) enc cvt: float4 -> f16x4.
//  (3) LN (prep-LN1 + ln_kernel): float2 in, f16x2 out.
//  (4) q2kv2 merge: kv2's 80 blocks FIRST so they overlap q2 from t=0
//      (were queued behind 512 q2 blocks at 2-blocks/CU).
// GEMMs/attn byte-identical to R20.
// ---------------------------------------------------------------------------

typedef _Float16 half8 __attribute__((ext_vector_type(8)));
typedef _Float16 half2v __attribute__((ext_vector_type(2)));
typedef _Float16 half4v __attribute__((ext_vector_type(4)));
typedef float f32x4 __attribute__((ext_vector_type(4)));

__device__ __forceinline__ f32x4 mfma16(half8 a, half8 b, f32x4 c) {
  return __builtin_amdgcn_mfma_f32_16x16x32_f16(a, b, c, 0, 0, 0);
}

__device__ __forceinline__ void gload16(const _Float16* g, _Float16* l) {
  __builtin_amdgcn_global_load_lds(
      (const __attribute__((address_space(1))) void*)g,
      (__attribute__((address_space(3))) void*)l, 16, 0, 0);
}

template <int N>
__device__ __forceinline__ void wait_vmcnt() {
  if constexpr (N == 0)
    asm volatile("s_waitcnt vmcnt(0)" ::: "memory");
  else if constexpr (N == 1)
    asm volatile("s_waitcnt vmcnt(1)" ::: "memory");
  else if constexpr (N == 2)
    asm volatile("s_waitcnt vmcnt(2)" ::: "memory");
  else if constexpr (N == 3)
    asm volatile("s_waitcnt vmcnt(3)" ::: "memory");
  else if constexpr (N == 4)
    asm volatile("s_waitcnt vmcnt(4)" ::: "memory");
  else
    static_assert(N <= 4, "add a case");
}

// ---------------- fused prep: 10 weight transposes + enc cvt + LN1 ---------
// Transposes: 64x64 f32 tiles, float2 reads (8B/lane), f16x2 writes (4B/lane).
struct PrepArgs {
  const float* src[10];
  _Float16* dst[10];
  int K[10], N[10], base[10];
  const float* enc;
  _Float16* ench;
  int encBase, nEnc;
  const float* x;
  const float* ln1g;
  const float* ln1b;
  _Float16* hbuf;
  int lnBase;  // first block index of LN rows (8192 rows follow)
};

__global__ __launch_bounds__(256)
void prep_all(PrepArgs pa) {
  __shared__ float tile[64][65];
  const int bid = blockIdx.x;
  const int tx = threadIdx.x, ty = threadIdx.y;
  const int t = ty * 32 + tx;
  if (bid >= pa.lnBase) {
    // -------- LayerNorm1 row (float2 in, f16x2 out) --------
    const int row = bid - pa.lnBase;
    const float* xr = pa.x + (size_t)row * 512;
    const float2 v = *(const float2*)(xr + t * 2);
    float s1 = v.x + v.y, s2 = v.x * v.x + v.y * v.y;
    #pragma unroll
    for (int m = 32; m >= 1; m >>= 1) {
      s1 += __shfl_xor(s1, m);
      s2 += __shfl_xor(s2, m);
    }
    __shared__ float red[8];
    if ((t & 63) == 0) { red[t >> 6] = s1; red[4 + (t >> 6)] = s2; }
    __syncthreads();
    s1 = red[0] + red[1] + red[2] + red[3];
    s2 = red[4] + red[5] + red[6] + red[7];
    const float mu = s1 * (1.0f / 512.0f);
    const float var = s2 * (1.0f / 512.0f) - mu * mu;
    const float rs = rsqrtf(var + 1e-5f);
    const float2 gv = *(const float2*)(pa.ln1g + t * 2);
    const float2 bv = *(const float2*)(pa.ln1b + t * 2);
    half2v pk;
    pk[0] = (_Float16)((v.x - mu) * rs * gv.x + bv.x);
    pk[1] = (_Float16)((v.y - mu) * rs * gv.y + bv.y);
    *(half2v*)(&pa.hbuf[(size_t)row * 512 + t * 2]) = pk;
    return;
  }
  if (bid >= pa.encBase) {
    const int i4 = (bid - pa.encBase) * 1024 + t * 4;
    if (i4 < pa.nEnc) {
      const float4 e = *(const float4*)(pa.enc + i4);
      half4v pk;
      pk[0] = (_Float16)e.x; pk[1] = (_Float16)e.y;
      pk[2] = (_Float16)e.z; pk[3] = (_Float16)e.w;
      *(half4v*)(&pa.ench[i4]) = pk;
    }
    return;
  }
  int mi = 0;
  #pragma unroll
  for (int j = 1; j < 10; j++)
    if (bid >= pa.base[j]) mi = j;
  const int K = pa.K[mi], N = pa.N[mi];
  const int rel = bid - pa.base[mi];
  const int ntiles = N >> 6;
  const int bx = rel % ntiles, by = rel / ntiles;
  const float* src = pa.src[mi];
  _Float16* dst = pa.dst[mi];
  const int n0 = bx * 64, k0 = by * 64;
  #pragma unroll
  for (int j = ty; j < 64; j += 8) {
    const float2 v = *(const float2*)(&src[(size_t)(k0 + j) * N + n0 + tx * 2]);
    tile[j][tx * 2] = v.x;
    tile[j][tx * 2 + 1] = v.y;
  }
  __syncthreads();
  #pragma unroll
  for (int j = ty; j < 64; j += 8) {
    half2v pk;
    pk[0] = (_Float16)tile[tx * 2][j];
    pk[1] = (_Float16)tile[tx * 2 + 1][j];
    *(half2v*)(&dst[(size_t)(n0 + j) * K + k0 + tx * 2]) = pk;
  }
}

// ---------------- V transpose: [b*S+s][h*64+d] -> [(bh*64)+d][s] -----------
__global__ __launch_bounds__(256)
void vt_kernel(const _Float16* __restrict__ src, _Float16* __restrict__ dst,
               int S, int srcStride, int dstStride) {
  __shared__ _Float16 tile[32][33];
  const int tx = threadIdx.x, ty = threadIdx.y;  // (32,8)
  const int s0 = blockIdx.x * 32, d0 = blockIdx.y * 32, bh = blockIdx.z;
  const int b = bh >> 3, h = bh & 7;
  const _Float16* sp = src + (size_t)b * S * srcStride + h * 64 + d0;
  #pragma unroll
  for (int j = ty; j < 32; j += 8) {
    int s = s0 + j; if (s >= S) s = S - 1;
    tile[j][tx] = sp[(size_t)s * srcStride + tx];
  }
  __syncthreads();
  _Float16* dp = dst + ((size_t)bh * 64 + d0) * dstStride + s0;
  #pragma unroll
  for (int j = ty; j < 32; j += 8)
    dp[(size_t)j * dstStride + tx] = tile[tx][j];
}

// ---------------- LayerNorm (row=512), fp32 in -> f16 out ------------------
// float2 in, f16x2 out (G13).
__global__ __launch_bounds__(256)
void ln_kernel(const float* __restrict__ x, const float* __restrict__ g,
               const float* __restrict__ b, _Float16* __restrict__ out) {
  const int row = blockIdx.x, t = threadIdx.x;
  const float* xr = x + (size_t)row * 512;
  const float2 v = *(const float2*)(xr + t * 2);
  float s1 = v.x + v.y, s2 = v.x * v.x + v.y * v.y;
  #pragma unroll
  for (int m = 32; m >= 1; m >>= 1) {
    s1 += __shfl_xor(s1, m);
    s2 += __shfl_xor(s2, m);
  }
  __shared__ float red[8];
  if ((t & 63) == 0) { red[t >> 6] = s1; red[4 + (t >> 6)] = s2; }
  __syncthreads();
  s1 = red[0] + red[1] + red[2] + red[3];
  s2 = red[4] + red[5] + red[6] + red[7];
  const float mu = s1 * (1.0f / 512.0f);
  const float var = s2 * (1.0f / 512.0f) - mu * mu;
  const float rs = rsqrtf(var + 1e-5f);
  const float2 gv = *(const float2*)(g + t * 2);
  const float2 bv = *(const float2*)(b + t * 2);
  half2v pk;
  pk[0] = (_Float16)((v.x - mu) * rs * gv.x + bv.x);
  pk[1] = (_Float16)((v.y - mu) * rs * gv.y + bv.y);
  *(half2v*)(&out[(size_t)row * 512 + t * 2]) = pk;
}

// ---------------- GEMM body: C = A[M,K] @ BT[N,K]^T ------------------------
// PIPE=0: 2-buffer __syncthreads loop. PIPE=1: 3-buffer counted-vmcnt.
// EPI 0: f16 store. EPI 1: Cf = resid + acc + bias. EPI 2: GEGLU dual
// (tanh-GELU). swz: runtime XCD swizzle flag.
template <int EPI, int GWM, int GWN, int WM, int WN, int PIPE>
__device__ __forceinline__ void gemm_body(
    int bid, int swz,
    const _Float16* A, const _Float16* BT,
    int M, int N, int K, int lda, int ldb, int ldc,
    _Float16* Ch, float* Cf, const float* bias, const float* resid) {
  constexpr int NW = GWM * GWN;
  constexpr int BM = GWM * WM * 16;
  constexpr int BN = GWN * WN * 16;
  constexpr int NBUF = PIPE ? 3 : 2;
  constexpr int LPT = (BM / 16) / NW + ((BN / 16) / NW) * ((EPI == 2) ? 2 : 1);
  __shared__ __align__(16) _Float16 As[NBUF][4 * BM * 8];
  __shared__ __align__(16) _Float16 Bs[NBUF][4 * BN * 8];
  __shared__ __align__(16) _Float16 Bs2[(EPI == 2) ? NBUF : 1]
                                      [(EPI == 2) ? 4 * BN * 8 : 8];

  const int t = threadIdx.x;
  const int NNB = (N + BN - 1) / BN;
  int bm, bn;
  if (swz) {
    const int MG = (M / BM) >> 3;
    const int xcd = bid & 7;
    const int s = bid >> 3;
    bm = xcd * MG + s % MG;
    bn = s / MG;
  } else {
    bn = bid % NNB;
    bm = bid / NNB;
  }
  const int m0 = bm * BM, n0 = bn * BN;
  const int lane = t & 63, wv = t >> 6;
  const int quad = lane >> 4, l15 = lane & 15;
  const int wm = wv / GWN, wn = wv % GWN;

  f32x4 zero4 = {0.f, 0.f, 0.f, 0.f};
  f32x4 acc[WM][WN];
  f32x4 acc2[(EPI == 2) ? WM : 1][(EPI == 2) ? WN : 1];
  #pragma unroll
  for (int mi = 0; mi < WM; mi++)
    #pragma unroll
    for (int ni = 0; ni < WN; ni++) acc[mi][ni] = zero4;
  if constexpr (EPI == 2) {
    #pragma unroll
    for (int mi = 0; mi < WM; mi++)
      #pragma unroll
      for (int ni = 0; ni < WN; ni++) acc2[mi][ni] = zero4;
  }

  auto stageAll = [&](int k0, int pb) {
    #pragma unroll
    for (int c = wv; c < BM / 16; c += NW) {
      const int s = c * 64 + lane;
      const int q = s / BM;
      const int r = s % BM;
      int rg = m0 + r; if (rg >= M) rg = M - 1;
      gload16(A + (size_t)rg * lda + k0 + q * 8, &As[pb][c * 512]);
    }
    #pragma unroll
    for (int c = wv; c < BN / 16; c += NW) {
      const int s = c * 64 + lane;
      const int q = s / BN;
      const int r = s % BN;
      gload16(BT + (size_t)(n0 + r) * ldb + k0 + q * 8, &Bs[pb][c * 512]);
      if constexpr (EPI == 2)
        gload16(BT + (size_t)(2048 + n0 + r) * ldb + k0 + q * 8,
                &Bs2[pb][c * 512]);
    }
  };

  auto computeTile = [&](int cur) {
    half8 fa[WM], fb[WN], fb2[(EPI == 2) ? WN : 1];
    #pragma unroll
    for (int mi = 0; mi < WM; mi++)
      fa[mi] = *(const half8*)(&As[cur]
          [((size_t)quad * BM + wm * WM * 16 + mi * 16 + l15) * 8]);
    #pragma unroll
    for (int ni = 0; ni < WN; ni++) {
      fb[ni] = *(const half8*)(&Bs[cur]
          [((size_t)quad * BN + wn * WN * 16 + ni * 16 + l15) * 8]);
      if constexpr (EPI == 2)
        fb2[ni] = *(const half8*)(&Bs2[cur]
            [((size_t)quad * BN + wn * WN * 16 + ni * 16 + l15) * 8]);
    }
    if constexpr (PIPE) __builtin_amdgcn_s_setprio(1);
    #pragma unroll
    for (int mi = 0; mi < WM; mi++)
      #pragma unroll
      for (int ni = 0; ni < WN; ni++) {
        acc[mi][ni] = mfma16(fa[mi], fb[ni], acc[mi][ni]);
        if constexpr (EPI == 2)
          acc2[mi][ni] = mfma16(fa[mi], fb2[ni], acc2[mi][ni]);
      }
    if constexpr (PIPE) __builtin_amdgcn_s_setprio(0);
  };

  const int NIT = K >> 5;
  if constexpr (PIPE) {
    // 3-buffer stage-ahead-2, counted vmcnt.
    stageAll(0, 0);
    if (NIT > 1) stageAll(32, 1);
    int cur = 0, pre = 2;
    for (int it = 0; it < NIT; ++it) {
      if (it + 1 < NIT) wait_vmcnt<LPT>();
      else wait_vmcnt<0>();
      __builtin_amdgcn_s_barrier();
      __builtin_amdgcn_sched_barrier(0);
      computeTile(cur);
      asm volatile("s_waitcnt lgkmcnt(0)" ::: "memory");
      __builtin_amdgcn_sched_barrier(0);
      __builtin_amdgcn_s_barrier();
      if (it + 2 < NIT) stageAll((it + 2) << 5, pre);
      cur = (cur == 2) ? 0 : cur + 1;
      pre = (pre == 2) ? 0 : pre + 1;
    }
  } else {
    // 2-buffer __syncthreads loop.
    stageAll(0, 0);
    __syncthreads();
    for (int it = 0; it < NIT; ++it) {
      const int cur = it & 1;
      if (it + 1 < NIT) stageAll((it + 1) << 5, cur ^ 1);
      computeTile(cur);
      __syncthreads();
    }
  }

  #pragma unroll
  for (int mi = 0; mi < WM; mi++) {
    const int rbase = m0 + wm * WM * 16 + mi * 16 + quad * 4;
    #pragma unroll
    for (int r = 0; r < 4; r++) {
      const int row = rbase + r;
      if (row >= M) continue;
      #pragma unroll
      for (int ni = 0; ni < WN; ni++) {
        const int col = n0 + wn * WN * 16 + ni * 16 + l15;
        const float v = acc[mi][ni][r];
        if constexpr (EPI == 0) {
          Ch[(size_t)row * ldc + col] = (_Float16)v;
        } else if constexpr (EPI == 1) {
          Cf[(size_t)row * ldc + col] =
              resid[(size_t)row * ldc + col] + v + bias[col];
        } else {
          const float u = v + bias[col];
          const float gg = acc2[mi][ni][r] + bias[col + 2048];
          // tanh-approx GELU: 1 exp + 1 rcp + ~6 fma (vs erff ~25-30 ops).
          const float z = 0.7978845608f * gg * (1.0f + 0.044715f * gg * gg);
          const float e2 = exp2f(z * 2.885390082f);   // e^(2z)
          const float th = 1.0f - 2.0f * __builtin_amdgcn_rcpf(e2 + 1.0f);
          const float ge = 0.5f * gg * (1.0f + th);
          Ch[(size_t)row * ldc + col] = (_Float16)(u * ge);
        }
      }
    }
  }
}

template <int EPI, int GWM, int GWN, int WM, int WN, int MW, int SWZ,
          int PIPE>
__global__ __launch_bounds__(GWM * GWN * 64, MW)
void gemm_bt(const _Float16* __restrict__ A, const _Float16* __restrict__ BT,
             int M, int N, int K, int lda, int ldb, int ldc,
             _Float16* Ch, float* Cf,
             const float* __restrict__ bias, const float* resid) {
  gemm_body<EPI, GWM, GWN, WM, WN, PIPE>(blockIdx.x, SWZ, A, BT, M, N, K,
                                         lda, ldb, ldc, Ch, Cf, bias, resid);
}

// Merged kv2 (80 blocks FIRST, so they overlap q2 from t=0) + q2 (512
// swizzled blocks). Same instantiation both branches -> one LDS allocation;
// branch is block-uniform.
__global__ __launch_bounds__(1024, 8)
void gemm_q2kv2(const _Float16* hbuf, const _Float16* q2T, _Float16* q2b,
                const _Float16* ench, const _Float16* kv2T, _Float16* kv2b) {
  if (blockIdx.x < 80)
    gemm_body<0, 4, 4, 1, 2, 0>(blockIdx.x, 0, ench, kv2T,
                                616, 1024, 768, 768, 768, 1024,
                                kv2b, nullptr, nullptr, nullptr);
  else
    gemm_body<0, 4, 4, 1, 2, 0>(blockIdx.x - 80, 1, hbuf, q2T,
                                8192, 512, 512, 512, 512, 512,
                                q2b, nullptr, nullptr, nullptr);
}

// ---------------- flash attention v2: 8 waves x 16 Q-rows, 3-buffer --------
// 512 threads. Waves 0-3 stage K tile (32sk x 64d), waves 4-7 stage VT tile
// (64d x 32sk); 1 gload16/thread/stage. Grid (Sq/128, B*H) -> 16 waves/CU.
__global__ __launch_bounds__(512)
void attn2(const _Float16* __restrict__ Q, const _Float16* __restrict__ K,
           const _Float16* __restrict__ VT, _Float16* __restrict__ O,
           int qStride, int kStride, long kBatchStride,
           int vtStride, int Sk) {
  __shared__ __align__(16) _Float16 KsL[3][2048];
  __shared__ __align__(16) _Float16 VTsL[3][2048];
  __shared__ __align__(16) _Float16 Ps[8][16][40];

  const int t = threadIdx.x;
  const int w = t >> 6, lane = t & 63, quad = lane >> 4, l15 = lane & 15;
  const int bh = blockIdx.y, b = bh >> 3, h = bh & 7;
  const int q0 = blockIdx.x * 128 + w * 16;

  const _Float16 qscale = (_Float16)(0.125f * 1.44269504f);
  half8 qf[2];
  #pragma unroll
  for (int c = 0; c < 2; c++) {
    const _Float16* qp = Q + (size_t)(b * 1024 + q0 + l15) * qStride +
                         h * 64 + c * 32 + quad * 8;
    half8 v = *(const half8*)qp;
    #pragma unroll
    for (int j = 0; j < 8; j++) v[j] *= qscale;
    qf[c] = v;
  }

  f32x4 zero4 = {0.f, 0.f, 0.f, 0.f};
  f32x4 oa[4];
  float psum[4];
  #pragma unroll
  for (int nt = 0; nt < 4; nt++) oa[nt] = zero4;
  #pragma unroll
  for (int r = 0; r < 4; r++) psum[r] = 0.f;

  const _Float16* kp = K + (size_t)b * kBatchStride + h * 64;
  const _Float16* vtp = VT + (size_t)bh * 64 * vtStride;
  const bool doK = (t < 256);               // wave-uniform
  const int ts = doK ? t : t - 256;
  const int ksk = ts & 31, kc = ts >> 7, kqd = (ts >> 5) & 3;
  const int vd = ts & 63, vqd = ts >> 6;

  auto stageKV = [&](int skb, int pb) {
    if (doK) {
      int skc = skb + ksk; if (skc >= Sk) skc = Sk - 1;
      gload16(kp + (size_t)skc * kStride + kc * 32 + kqd * 8,
              &KsL[pb][ts * 8]);
    } else {
      gload16(vtp + (size_t)vd * vtStride + skb + vqd * 8,
              &VTsL[pb][ts * 8]);
    }
  };

  const int NITa = (Sk + 31) >> 5;
  stageKV(0, 0);
  if (NITa > 1) stageKV(32, 1);

  int cur = 0, pre = 2;
  int it = 0;
  for (int skb = 0; skb < Sk; skb += 32, ++it) {
    if (it + 1 < NITa) wait_vmcnt<1>();
    else wait_vmcnt<0>();
    __builtin_amdgcn_s_barrier();
    __builtin_amdgcn_sched_barrier(0);

    const bool tail = (skb + 32 > Sk);
    #pragma unroll
    for (int ct = 0; ct < 2; ct++) {
      f32x4 s = zero4;
      half8 kb0 = *(const half8*)(&KsL[cur][(quad * 32 + ct * 16 + l15) * 8]);
      half8 kb1 =
          *(const half8*)(&KsL[cur][(128 + quad * 32 + ct * 16 + l15) * 8]);
      s = mfma16(qf[0], kb0, s);
      s = mfma16(qf[1], kb1, s);
      if (tail) {
        const bool valid = (skb + ct * 16 + l15) < Sk;
        #pragma unroll
        for (int r = 0; r < 4; r++)
          if (!valid) s[r] = -__builtin_inff();
      }
      #pragma unroll
      for (int r = 0; r < 4; r++) {
        const float e = exp2f(s[r]);
        psum[r] += e;
        Ps[w][quad * 4 + r][ct * 16 + l15] = (_Float16)e;
      }
    }
    {
      const half8 pf = *(const half8*)(&Ps[w][l15][quad * 8]);
      #pragma unroll
      for (int nt = 0; nt < 4; nt++) {
        const half8 vf =
            *(const half8*)(&VTsL[cur][(quad * 64 + nt * 16 + l15) * 8]);
        oa[nt] = mfma16(pf, vf, oa[nt]);
      }
    }

    asm volatile("s_waitcnt lgkmcnt(0)" ::: "memory");
    __builtin_amdgcn_sched_barrier(0);
    __builtin_amdgcn_s_barrier();
    if (it + 2 < NITa) stageKV(skb + 64, pre);
    cur = (cur == 2) ? 0 : cur + 1;
    pre = (pre == 2) ? 0 : pre + 1;
  }

  #pragma unroll
  for (int r = 0; r < 4; r++) {
    #pragma unroll
    for (int mm = 1; mm < 16; mm <<= 1)
      psum[r] += __shfl_xor(psum[r], mm);
    psum[r] = 1.0f / psum[r];
  }

  #pragma unroll
  for (int nt = 0; nt < 4; nt++)
    #pragma unroll
    for (int r = 0; r < 4; r++) {
      const size_t row = (size_t)(b * 1024 + q0 + quad * 4 + r);
      O[row * 512 + h * 64 + nt * 16 + l15] =
          (_Float16)(oa[nt][r] * psum[r]);
    }
}

// ---------------------------------------------------------------------------
extern "C" void kernel_launch(void* const* d_in, const int* in_sizes, int n_in,
                              void* d_out, int out_size, void* d_ws,
                              size_t ws_size, hipStream_t stream) {
  const float* x    = (const float*)d_in[0];
  const float* enc  = (const float*)d_in[1];
  const float* ln1g = (const float*)d_in[2];
  const float* ln1b = (const float*)d_in[3];
  const float* wq1  = (const float*)d_in[4];
  const float* wk1  = (const float*)d_in[5];
  const float* wv1  = (const float*)d_in[6];
  const float* wo1  = (const float*)d_in[7];
  const float* bo1  = (const float*)d_in[8];
  const float* ln2g = (const float*)d_in[9];
  const float* ln2b = (const float*)d_in[10];
  const float* wq2  = (const float*)d_in[11];
  const float* wk2  = (const float*)d_in[12];
  const float* wv2  = (const float*)d_in[13];
  const float* wo2  = (const float*)d_in[14];
  const float* bo2  = (const float*)d_in[15];
  const float* ln3g = (const float*)d_in[16];
  const float* ln3b = (const float*)d_in[17];
  const float* wg   = (const float*)d_in[18];
  const float* bg   = (const float*)d_in[19];
  const float* wf   = (const float*)d_in[20];
  const float* bfp  = (const float*)d_in[21];
  float* out = (float*)d_out;

  char* ws = (char*)d_ws;
  _Float16* qkvT  = (_Float16*)(ws + 0);         // [1536,512]
  _Float16* q2T   = (_Float16*)(ws + 1572864);   // [512,512]
  _Float16* kv2T  = (_Float16*)(ws + 2097152);   // [1024,768]
  _Float16* wo1T  = (_Float16*)(ws + 3670016);   // [512,512]
  _Float16* wo2T  = (_Float16*)(ws + 4194304);   // [512,512]
  _Float16* wgT   = (_Float16*)(ws + 4718592);   // [4096,512]
  _Float16* wfT   = (_Float16*)(ws + 8912896);   // [512,2048]
  _Float16* hbuf  = (_Float16*)(ws + 11010048);  // [8192,512] (VTself in attn1)
  _Float16* qkv   = (_Float16*)(ws + 19398656);  // [8192,1536]
  _Float16* q2b   = (_Float16*)(ws + 44564480);  // [8192,512]
  _Float16* kv2b  = (_Float16*)(ws + 52953088);  // [616,1024]
  _Float16* attnb = (_Float16*)(ws + 54214656);  // [8192,512]
  _Float16* ench  = (_Float16*)(ws + 62603264);  // [616,768]
  _Float16* ffb   = (_Float16*)(ws + 19398656);  // [8192,2048] aliases qkv+q2b
  _Float16* VTself = hbuf;                       // [4096,1024]
  _Float16* VTc   = (_Float16*)(ws + 62603264);  // [4096,96] over ench (dead
                                                 // after kv2 GEMM)

  // ---- fused prep: weights + enc + LN1 (one launch) ----
  PrepArgs pa;
  const float* srcs[10] = {wq1, wk1, wv1, wo1, wq2, wk2, wv2, wo2, wg, wf};
  _Float16* dsts[10] = {qkvT, qkvT + 512 * 512, qkvT + 1024 * 512, wo1T, q2T,
                        kv2T, kv2T + 512 * 768, wo2T, wgT, wfT};
  const int Ks[10] = {512, 512, 512, 512, 512, 768, 768, 512, 512, 2048};
  const int Ns[10] = {512, 512, 512, 512, 512, 512, 512, 512, 4096, 512};
  int base = 0;
  for (int i = 0; i < 10; i++) {
    pa.src[i] = srcs[i]; pa.dst[i] = dsts[i];
    pa.K[i] = Ks[i]; pa.N[i] = Ns[i]; pa.base[i] = base;
    base += (Ks[i] >> 6) * (Ns[i] >> 6);
  }
  pa.enc = enc; pa.ench = ench; pa.encBase = base; pa.nEnc = 473088;
  base += (473088 + 1023) / 1024;
  pa.x = x; pa.ln1g = ln1g; pa.ln1b = ln1b; pa.hbuf = hbuf; pa.lnBase = base;
  base += 8192;
  prep_all<<<base, dim3(32, 8), 0, stream>>>(pa);

  const dim3 tb(32, 8);

  // ---- self-attention block ----
  // QKV: 128x128 tile, 8 waves, grid 768 (R16/R18)
  gemm_bt<0, 2, 4, 4, 2, 4, 1, 0><<<768, 512, 0, stream>>>(
      hbuf, qkvT, 8192, 1536, 512, 512, 512, 1536,
      qkv, nullptr, nullptr, nullptr);
  vt_kernel<<<dim3(32, 2, 64), tb, 0, stream>>>(qkv + 1024, VTself, 1024,
                                                1536, 1024);
  attn2<<<dim3(8, 64), 512, 0, stream>>>(qkv, qkv + 512, VTself, attnb,
                                         1536, 1536, (long)1024 * 1536,
                                         1024, 1024);
  // wo1: 64x128 tile, 16 waves, grid 512 -> 32 waves/CU (R17)
  gemm_bt<1, 4, 4, 1, 2, 8, 1, 0><<<512, 1024, 0, stream>>>(
      attnb, wo1T, 8192, 512, 512, 512, 512, 512, nullptr, out, bo1, x);

  // ---- cross-attention block ----
  ln_kernel<<<8192, 256, 0, stream>>>(out, ln2g, ln2b, hbuf);
  // kv2 (80, first) + q2 (512, swizzled) merged (R18/R21)
  gemm_q2kv2<<<592, 1024, 0, stream>>>(hbuf, q2T, q2b, ench, kv2T, kv2b);
  vt_kernel<<<dim3(3, 2, 64), tb, 0, stream>>>(kv2b + 512, VTc, 77, 1024, 96);
  attn2<<<dim3(8, 64), 512, 0, stream>>>(q2b, kv2b, VTc, attnb,
                                         512, 1024, (long)77 * 1024, 96, 77);
  gemm_bt<1, 4, 4, 1, 2, 8, 1, 0><<<512, 1024, 0, stream>>>(
      attnb, wo2T, 8192, 512, 512, 512, 512, 512, nullptr, out, bo2, out);

  // ---- GEGLU feed-forward ----
  ln_kernel<<<8192, 256, 0, stream>>>(out, ln3g, ln3b, hbuf);
  // GEGLU: 128x128-dual, 8 waves (R14 config) + tanh-GELU epilogue (R18).
  // WM4xWN2-dual = 0.5 ds_read/MFMA, the optimum under the 64-acc-reg cap.
  gemm_bt<2, 2, 4, 4, 2, 4, 1, 0><<<1024, 512, 0, stream>>>(
      hbuf, wgT, 8192, 2048, 512, 512, 512, 2048,
      ffb, nullptr, bg, nullptr);
  // wf: 64x128 tile, 16 waves, grid 512 -> 32 waves/CU (R17)
  gemm_bt<1, 4, 4, 1, 2, 8, 1, 0><<<512, 1024, 0, stream>>>(
      ffb, wfT, 8192, 512, 2048, 2048, 2048, 512,
      nullptr, out, bfp, out);
}